// Round 8
// baseline (222.934 us; speedup 1.0000x reference)
//
#include <hip/hip_runtime.h>

#define MWIN 2048
#define HH 8

typedef _Float16 half8 __attribute__((ext_vector_type(8)));
typedef _Float16 half4 __attribute__((ext_vector_type(4)));
typedef float f32x4 __attribute__((ext_vector_type(4)));

// ---------------- weight fp32 -> fp16 (both weights, one launch) ----------------
__global__ __launch_bounds__(256) void k_cvt_w(const float* __restrict__ Wqkv,
                                               const float* __restrict__ Wproj,
                                               _Float16* __restrict__ Wqkv_h,
                                               _Float16* __restrict__ Wp_h) {
    int i = blockIdx.x * 256 + threadIdx.x;   // half8 id; 6144 for Wqkv, 2048 for Wproj
    const float* src; _Float16* dst; int j;
    if (i < 6144) { src = Wqkv; dst = Wqkv_h; j = i; }
    else if (i < 8192) { src = Wproj; dst = Wp_h; j = i - 6144; }
    else return;
    float4 a = ((const float4*)src)[j * 2];
    float4 b = ((const float4*)src)[j * 2 + 1];
    half8 h;
    h[0] = (_Float16)a.x; h[1] = (_Float16)a.y; h[2] = (_Float16)a.z; h[3] = (_Float16)a.w;
    h[4] = (_Float16)b.x; h[5] = (_Float16)b.y; h[6] = (_Float16)b.z; h[7] = (_Float16)b.w;
    ((half8*)dst)[j] = h;
}

// ---- MFMA GEMM, K=128, A=W (m=outdim), B=points (n). B-frags loaded once/block. ----
// Block: 4 waves x 64 points = 256 points; loop over nmg 64-outdim groups.
// D: row=q*4+reg = outdim (4 consecutive) -> vectorized half4/float4 stores.
template <typename IN_T, typename OUT_T>
__global__ __launch_bounds__(256) void k_mfma_gemm(const IN_T* __restrict__ X,
                                                   const _Float16* __restrict__ Bw,
                                                   const float* __restrict__ bias,
                                                   OUT_T* __restrict__ out, int ldo,
                                                   int N, int nmg) {
    int tid = threadIdx.x;
    int lane = tid & 63, wv = tid >> 6;
    int m = lane & 15, q = lane >> 4;
    int pt0 = blockIdx.x * 256 + wv * 64;

    // B fragments: 4 point-tiles x 4 k-steps, held in regs for the whole kernel
    half8 b[4][4];
    #pragma unroll
    for (int nt = 0; nt < 4; ++nt) {
        int p = pt0 + nt * 16 + m;
        p = p < N ? p : N - 1;
        const IN_T* xp = X + (size_t)p * 128 + q * 8;
        #pragma unroll
        for (int ks = 0; ks < 4; ++ks) {
            if constexpr (__is_same(IN_T, float)) {
                float4 f0 = *(const float4*)(xp + ks * 32);
                float4 f1 = *(const float4*)(xp + ks * 32 + 4);
                half8 h;
                h[0] = (_Float16)f0.x; h[1] = (_Float16)f0.y; h[2] = (_Float16)f0.z; h[3] = (_Float16)f0.w;
                h[4] = (_Float16)f1.x; h[5] = (_Float16)f1.y; h[6] = (_Float16)f1.z; h[7] = (_Float16)f1.w;
                b[nt][ks] = h;
            } else {
                b[nt][ks] = *(const half8*)(xp + ks * 32);
            }
        }
    }

    for (int mg = 0; mg < nmg; ++mg) {
        int od0 = mg * 64;
        f32x4 acc[4][4];
        #pragma unroll
        for (int mt = 0; mt < 4; ++mt) {
            f32x4 bv = {0.f, 0.f, 0.f, 0.f};
            if (bias) bv = *(const f32x4*)(bias + od0 + mt * 16 + q * 4);
            #pragma unroll
            for (int nt = 0; nt < 4; ++nt) acc[mt][nt] = bv;
        }
        #pragma unroll
        for (int ks = 0; ks < 4; ++ks) {
            half8 a[4];
            #pragma unroll
            for (int mt = 0; mt < 4; ++mt)
                a[mt] = *(const half8*)(Bw + (size_t)(od0 + mt * 16 + m) * 128 + q * 8 + ks * 32);
            #pragma unroll
            for (int mt = 0; mt < 4; ++mt)
                #pragma unroll
                for (int nt = 0; nt < 4; ++nt)
                    acc[mt][nt] = __builtin_amdgcn_mfma_f32_16x16x32_f16(a[mt], b[nt][ks], acc[mt][nt], 0, 0, 0);
        }
        #pragma unroll
        for (int nt = 0; nt < 4; ++nt) {
            int p = pt0 + nt * 16 + m;
            if (p >= N) continue;
            #pragma unroll
            for (int mt = 0; mt < 4; ++mt) {
                if constexpr (__is_same(OUT_T, float)) {
                    *(f32x4*)(out + (size_t)p * ldo + od0 + mt * 16 + q * 4) = acc[mt][nt];
                } else {
                    half4 hv;
                    hv[0] = (_Float16)acc[mt][nt][0]; hv[1] = (_Float16)acc[mt][nt][1];
                    hv[2] = (_Float16)acc[mt][nt][2]; hv[3] = (_Float16)acc[mt][nt][3];
                    *(half4*)(out + (size_t)p * ldo + od0 + mt * 16 + q * 4) = hv;
                }
            }
        }
    }
}

// ---- per-(window,head) kv & s reduction; wave per (w, 2h), no LDS/barriers ----
__global__ __launch_bounds__(256) void k_kv_accum(const _Float16* __restrict__ qkv,
                                                  const int* __restrict__ offsets,
                                                  const int* __restrict__ counts,
                                                  float* __restrict__ kv_t,
                                                  float* __restrict__ s) {
    int w = blockIdx.x;
    int wv = threadIdx.x >> 6, lane = threadIdx.x & 63;
    int d = lane & 15, eq = lane >> 4;
    int off = offsets[w], cnt = counts[w];
    #pragma unroll
    for (int hh = 0; hh < 2; ++hh) {
        int h = wv * 2 + hh;
        float acc0 = 0.f, acc1 = 0.f, acc2 = 0.f, acc3 = 0.f, sacc = 0.f;
        const _Float16* base = qkv + (size_t)off * 384 + h * 16;
        for (int p = 0; p < cnt; ++p) {
            const _Float16* row = base + (size_t)p * 384;
            float kk = (float)row[128 + d];
            kk = kk > 0.f ? kk : 0.f;
            half4 v4 = *(const half4*)(row + 256 + eq * 4);
            acc0 += kk * (float)v4[0];
            acc1 += kk * (float)v4[1];
            acc2 += kk * (float)v4[2];
            acc3 += kk * (float)v4[3];
            sacc += kk;
        }
        float* o = kv_t + (((size_t)(w * HH + h)) << 8);
        o[(eq * 4 + 0) * 16 + d] = acc0;
        o[(eq * 4 + 1) * 16 + d] = acc1;
        o[(eq * 4 + 2) * 16 + d] = acc2;
        o[(eq * 4 + 3) * 16 + d] = acc3;
        if (eq == 0) s[(((size_t)(w * HH + h)) << 4) + d] = sacc;
    }
}

// ------- fused 3x3 pool: fp32 in -> fp16 out, float4-granular -------
#define KV4 (MWIN * 512)
#define S4  (MWIN * 32)
__global__ __launch_bounds__(256) void k_pool_all(const float* __restrict__ kv_in,
                                                  _Float16* __restrict__ kv_out,
                                                  const float* __restrict__ s_in,
                                                  _Float16* __restrict__ s_out) {
    int idx = blockIdx.x * 256 + threadIdx.x;
    const float* in;
    _Float16* outp;
    int w, rest, shift;
    if (idx < KV4) {
        w = idx >> 9; rest = idx & 511; shift = 9;
        in = kv_in; outp = kv_out;
    } else {
        int j = idx - KV4;
        if (j >= S4) return;
        w = j >> 5; rest = j & 31; shift = 5;
        in = s_in; outp = s_out;
        idx = j;
    }
    int b = w >> 10, y = (w >> 5) & 31, xx = w & 31;
    f32x4 acc = {0.f, 0.f, 0.f, 0.f};
    #pragma unroll
    for (int dy = -1; dy <= 1; ++dy)
        #pragma unroll
        for (int dx = -1; dx <= 1; ++dx) {
            int ny = y + dy, nx = xx + dx;
            if (ny < 0 || ny >= 32 || nx < 0 || nx >= 32) continue;
            int nw = (b << 10) | (ny << 5) | nx;
            f32x4 v = ((const f32x4*)in)[((size_t)nw << shift) + rest];
            acc += v;
        }
    half4 hv;
    hv[0] = (_Float16)acc[0]; hv[1] = (_Float16)acc[1];
    hv[2] = (_Float16)acc[2]; hv[3] = (_Float16)acc[3];
    ((half4*)outp)[idx] = hv;
}

// ---------------- linear attention: one wave per window, MFMA-based ----------------
__global__ __launch_bounds__(256) void k_attn(const _Float16* __restrict__ qkv,
                                              const _Float16* __restrict__ kvp,
                                              const _Float16* __restrict__ sp,
                                              const int* __restrict__ offsets,
                                              const int* __restrict__ counts,
                                              _Float16* __restrict__ y_h) {
    int w = blockIdx.x * 4 + (threadIdx.x >> 6);
    int lane = threadIdx.x & 63;
    int col = lane & 15;
    int kq = lane >> 4;
    int off = offsets[w], cnt = counts[w];
    bool klive = kq < 2;
    int koff = (kq & 1) * 8;
    half8 zf = {};
    for (int h = 0; h < 8; ++h) {
        half8 t = *(const half8*)(kvp + ((((size_t)(w * HH + h)) << 8) + col * 16 + koff));
        half8 a_kv = klive ? t : zf;
        half8 t2 = *(const half8*)(sp + ((((size_t)(w * HH + h)) << 4) + koff));
        half8 a_s = klive ? t2 : zf;
        #pragma unroll
        for (int c = 0; c < 3; ++c) {
            int p = c * 16 + col;
            int pc = p < cnt ? p : cnt - 1;
            half8 qv = *(const half8*)(qkv + (size_t)(off + pc) * 384 + h * 16 + koff);
            #pragma unroll
            for (int i = 0; i < 8; ++i) qv[i] = qv[i] > (_Float16)0 ? qv[i] : (_Float16)0;
            half8 b_q = klive ? qv : zf;
            f32x4 acc = {};
            acc = __builtin_amdgcn_mfma_f32_16x16x32_f16(a_kv, b_q, acc, 0, 0, 0);
            f32x4 accs = {};
            accs = __builtin_amdgcn_mfma_f32_16x16x32_f16(a_s, b_q, accs, 0, 0, 0);
            float zinv = 1.f / (accs[0] + 1e-6f);
            half4 yo;
            #pragma unroll
            for (int i = 0; i < 4; ++i) yo[i] = (_Float16)(acc[i] * zinv);
            if (p < cnt)
                *(half4*)(y_h + (size_t)(off + p) * 128 + h * 16 + kq * 4) = yo;
        }
    }
}

extern "C" void kernel_launch(void* const* d_in, const int* in_sizes, int n_in,
                              void* d_out, int out_size, void* d_ws, size_t ws_size,
                              hipStream_t stream) {
    const float* x     = (const float*)d_in[0];
    const float* Wqkv  = (const float*)d_in[1];
    const float* Wproj = (const float*)d_in[2];
    const float* bproj = (const float*)d_in[3];
    const int*   offsets = (const int*)d_in[4];
    const int*   counts  = (const int*)d_in[5];

    int N = in_sizes[0] / 128;

    char* ws = (char*)d_ws;
    float* kv_t = (float*)ws;                                    ws += (size_t)MWIN * HH * 256 * 4;
    float* s    = (float*)ws;                                    ws += (size_t)MWIN * HH * 16 * 4;
    _Float16* kvpt = (_Float16*)ws;                              ws += (size_t)MWIN * HH * 256 * 2;
    _Float16* sp   = (_Float16*)ws;                              ws += (size_t)MWIN * HH * 16 * 2;
    _Float16* qkv_h  = (_Float16*)ws;                            ws += (size_t)N * 384 * 2;
    _Float16* y_h    = (_Float16*)ws;                            ws += (size_t)N * 128 * 2;
    _Float16* Wqkv_h = (_Float16*)ws;                            ws += (size_t)384 * 128 * 2;
    _Float16* Wp_h   = (_Float16*)ws;                            ws += (size_t)128 * 128 * 2;
    float* out  = (float*)d_out;

    k_cvt_w<<<32, 256, 0, stream>>>(Wqkv, Wproj, Wqkv_h, Wp_h);

    k_mfma_gemm<float, _Float16><<<(N + 255) / 256, 256, 0, stream>>>(x, Wqkv_h, nullptr, qkv_h, 384, N, 6);

    k_kv_accum<<<MWIN, 256, 0, stream>>>(qkv_h, offsets, counts, kv_t, s);

    k_pool_all<<<(KV4 + S4 + 255) / 256, 256, 0, stream>>>(kv_t, kvpt, s, sp);

    k_attn<<<MWIN / 4, 256, 0, stream>>>(qkv_h, kvpt, sp, offsets, counts, y_h);

    k_mfma_gemm<_Float16, float><<<(N + 255) / 256, 256, 0, stream>>>(y_h, Wp_h, bproj, out, 128, N, 2);
}